// Round 3
// baseline (367.230 us; speedup 1.0000x reference)
//
#include <hip/hip_runtime.h>
#include <math.h>

#define LSEQ 2048
#define DI 512
#define DS 64
#define DTRANK 8
#define CIN 128
#define NB 4
#define NC 8
#define TC 256

#if __has_builtin(__builtin_amdgcn_exp2f)
#define EXP2(x) __builtin_amdgcn_exp2f(x)
#else
#define EXP2(x) __expf((x) * 0.6931471805599453f)
#endif

__device__ __forceinline__ float silu_f(float v) { return v / (1.f + __expf(-v)); }

// ---------------- GEMM1: in_proj ----------------
__global__ __launch_bounds__(256) void gemm_inproj(
    const float* __restrict__ x, const float* __restrict__ Wi,
    float* __restrict__ xi_t, float* __restrict__ z_t) {
  __shared__ float As[16][68];  // [k][j]
  __shared__ float Bs[16][68];  // [k][l]
  int tid = threadIdx.x;
  int tx = tid & 15, ty = tid >> 4;
  int l0 = blockIdx.x * 64, j0 = blockIdx.y * 64, b = blockIdx.z;
  const float* xb = x + (size_t)b * CIN * LSEQ;
  float acc[4][4] = {};
  for (int k0 = 0; k0 < CIN; k0 += 16) {
    {
      int kk = tid & 15, jj = tid >> 4;
#pragma unroll
      for (int i = 0; i < 4; ++i)
        As[kk][jj + 16 * i] = Wi[(size_t)(j0 + jj + 16 * i) * CIN + k0 + kk];
    }
    {
      int ll = tid & 63, kk = tid >> 6;
#pragma unroll
      for (int i = 0; i < 4; ++i)
        Bs[kk + 4 * i][ll] = xb[(size_t)(k0 + kk + 4 * i) * LSEQ + l0 + ll];
    }
    __syncthreads();
#pragma unroll
    for (int k = 0; k < 16; ++k) {
      float4 a = *(const float4*)&As[k][ty * 4];
      float4 bv = *(const float4*)&Bs[k][tx * 4];
      float av[4] = {a.x, a.y, a.z, a.w};
      float bw[4] = {bv.x, bv.y, bv.z, bv.w};
#pragma unroll
      for (int i = 0; i < 4; ++i)
#pragma unroll
        for (int j = 0; j < 4; ++j) acc[i][j] = fmaf(av[i], bw[j], acc[i][j]);
    }
    __syncthreads();
  }
#pragma unroll
  for (int i = 0; i < 4; ++i) {
    int j = j0 + ty * 4 + i;
    int l = l0 + tx * 4;
    float4 v = make_float4(acc[i][0], acc[i][1], acc[i][2], acc[i][3]);
    if (j < DI)
      *(float4*)&xi_t[((size_t)(b * DI + j)) * LSEQ + l] = v;
    else
      *(float4*)&z_t[((size_t)(b * DI + (j - DI))) * LSEQ + l] = v;
  }
}

// ---------------- conv + silu -> u_t ----------------
__global__ __launch_bounds__(256) void conv_silu(
    const float* __restrict__ xi_t, const float* __restrict__ cw,
    const float* __restrict__ cb, float* __restrict__ u_t) {
  int idx = blockIdx.x * 256 + threadIdx.x;
  int l = idx & (LSEQ - 1);
  int d = (idx >> 11) & (DI - 1);
  int b = idx >> 20;
  const float* xp = xi_t + ((size_t)(b * DI + d)) * LSEQ;
  float acc = cb[d];
#pragma unroll
  for (int k = 0; k < 4; ++k) {
    int ll = l - 3 + k;
    if (ll >= 0) acc = fmaf(xp[ll], cw[d * 4 + k], acc);
  }
  u_t[idx] = silu_f(acc);
}

// ---------------- GEMM2: x_proj ----------------
__global__ __launch_bounds__(256) void gemm_xproj(
    const float* __restrict__ u_t, const float* __restrict__ Wx,
    float* __restrict__ dtr, float* __restrict__ Bb, float* __restrict__ Cb) {
  __shared__ float As[16][68];  // [d][l]
  __shared__ float Bs[16][68];  // [d][j]
  int tid = threadIdx.x;
  int tx = tid & 15, ty = tid >> 4;
  int l0 = blockIdx.x * 64, j0 = blockIdx.y * 64, b = blockIdx.z;
  const float* ub = u_t + (size_t)b * DI * LSEQ;
  float acc[4][4] = {};
  for (int k0 = 0; k0 < DI; k0 += 16) {
    {
      int ll = tid & 63, kk = tid >> 6;
#pragma unroll
      for (int i = 0; i < 4; ++i)
        As[kk + 4 * i][ll] = ub[(size_t)(k0 + kk + 4 * i) * LSEQ + l0 + ll];
    }
    {
      int kk = tid & 15, jj = tid >> 4;
#pragma unroll
      for (int i = 0; i < 4; ++i) {
        int j = j0 + jj + 16 * i;
        Bs[kk][jj + 16 * i] = (j < 136) ? Wx[(size_t)j * DI + k0 + kk] : 0.f;
      }
    }
    __syncthreads();
#pragma unroll
    for (int k = 0; k < 16; ++k) {
      float4 a = *(const float4*)&As[k][ty * 4];   // l dir
      float4 bv = *(const float4*)&Bs[k][tx * 4];  // j dir
      float av[4] = {a.x, a.y, a.z, a.w};
      float bw[4] = {bv.x, bv.y, bv.z, bv.w};
#pragma unroll
      for (int i = 0; i < 4; ++i)
#pragma unroll
        for (int j = 0; j < 4; ++j) acc[i][j] = fmaf(av[i], bw[j], acc[i][j]);
    }
    __syncthreads();
  }
#pragma unroll
  for (int i = 0; i < 4; ++i) {
    int l = l0 + ty * 4 + i;
    size_t bl = (size_t)b * LSEQ + l;
#pragma unroll
    for (int q = 0; q < 4; ++q) {
      int j = j0 + tx * 4 + q;
      float v = acc[i][q];
      if (j < DTRANK)
        dtr[bl * DTRANK + j] = v;
      else if (j < DTRANK + DS)
        Bb[bl * DS + (j - DTRANK)] = v;
      else if (j < DTRANK + 2 * DS)
        Cb[bl * DS + (j - DTRANK - DS)] = v;
    }
  }
}

// ---------------- dt GEMM (K=8) + softplus ----------------
__global__ __launch_bounds__(256) void dt_kernel(
    const float* __restrict__ dtr, const float* __restrict__ Wd,
    const float* __restrict__ db, float* __restrict__ dt_t) {
  int l = blockIdx.x * 256 + threadIdx.x;
  int d = blockIdx.y;
  int b = blockIdx.z;
  size_t bl = (size_t)b * LSEQ + l;
  float acc = db[d];
#pragma unroll
  for (int r = 0; r < DTRANK; ++r)
    acc = fmaf(dtr[bl * DTRANK + r], Wd[d * DTRANK + r], acc);
  float dtv = (acc > 20.f) ? acc : log1pf(__expf(acc));
  dt_t[((size_t)(b * DI + d)) * LSEQ + l] = dtv;
}

// ---------------- scan pass A: per-chunk (pa = prod dA, r = state from h0=0) ----------------
// block = 256 threads = 4 waves; wave w handles chunk c = blockIdx.y*4+w of channel d.
__global__ __launch_bounds__(256) void scan_partial(
    const float* __restrict__ dt_t, const float* __restrict__ u_t,
    const float* __restrict__ Bb, const float* __restrict__ A_log,
    float* __restrict__ pa_ws, float* __restrict__ r_ws) {
  int w = threadIdx.x >> 6, lane = threadIdx.x & 63;
  int d = blockIdx.x, b = blockIdx.z;
  int c = blockIdx.y * 4 + w;
  float An2 = -__expf(A_log[d * DS + lane]) * 1.4426950408889634f;
  size_t base = ((size_t)(b * DI + d)) * LSEQ + (size_t)c * TC;
  const float* dtp = dt_t + base;
  const float* up = u_t + base;
  const float* Bp = Bb + ((size_t)b * LSEQ + (size_t)c * TC) * DS;
  float h = 0.f, pa = 1.f;
  for (int ts = 0; ts < TC; ts += 16) {
    float dtv[16], uv[16], bv[16];
#pragma unroll
    for (int j = 0; j < 4; ++j) {
      float4 v = *(const float4*)&dtp[ts + 4 * j];
      dtv[4 * j] = v.x; dtv[4 * j + 1] = v.y; dtv[4 * j + 2] = v.z; dtv[4 * j + 3] = v.w;
      float4 u4 = *(const float4*)&up[ts + 4 * j];
      uv[4 * j] = u4.x; uv[4 * j + 1] = u4.y; uv[4 * j + 2] = u4.z; uv[4 * j + 3] = u4.w;
    }
#pragma unroll
    for (int i = 0; i < 16; ++i) bv[i] = Bp[(size_t)(ts + i) * DS + lane];
#pragma unroll
    for (int i = 0; i < 16; ++i) {
      float dA = EXP2(dtv[i] * An2);
      pa *= dA;
      h = fmaf(dA, h, (dtv[i] * uv[i]) * bv[i]);
    }
  }
  size_t o = (((size_t)(b * DI + d)) * NC + c) * DS + lane;
  pa_ws[o] = pa;
  r_ws[o] = h;
}

// ---------------- scan pass C: full scan per chunk with y output ----------------
// block = 128 threads = 2 waves; wave w handles chunk c = blockIdx.y*2+w.
// h_start folded in from upstream (pa, r) pairs. y-reduce every 16 steps via
// LDS transpose sp[16][68] (stride 68 -> balanced banks for b128 row reads).
__global__ __launch_bounds__(128) void scan_full(
    const float* __restrict__ dt_t, const float* __restrict__ u_t,
    const float* __restrict__ Bb, const float* __restrict__ Cb,
    const float* __restrict__ A_log, const float* __restrict__ pa_ws,
    const float* __restrict__ r_ws, float* __restrict__ y_t) {
  __shared__ __align__(16) float sp[2][16][68];
  int w = threadIdx.x >> 6, lane = threadIdx.x & 63;
  int d = blockIdx.x, b = blockIdx.z;
  int c = blockIdx.y * 2 + w;
  float An2 = -__expf(A_log[d * DS + lane]) * 1.4426950408889634f;
  size_t base = ((size_t)(b * DI + d)) * LSEQ + (size_t)c * TC;
  const float* dtp = dt_t + base;
  const float* up = u_t + base;
  const float* Bp = Bb + ((size_t)b * LSEQ + (size_t)c * TC) * DS;
  const float* Cp = Cb + ((size_t)b * LSEQ + (size_t)c * TC) * DS;
  float* yp = y_t + base;
  // fold h_start from upstream chunks
  float h = 0.f;
  size_t po = ((size_t)(b * DI + d)) * NC * DS + lane;
  for (int cc = 0; cc < c; ++cc)
    h = fmaf(pa_ws[po + (size_t)cc * DS], h, r_ws[po + (size_t)cc * DS]);
  int r = lane >> 2, q = lane & 3;
  for (int ts = 0; ts < TC; ts += 16) {
    float dtv[16], uv[16], bv[16], cv[16];
#pragma unroll
    for (int j = 0; j < 4; ++j) {
      float4 v = *(const float4*)&dtp[ts + 4 * j];
      dtv[4 * j] = v.x; dtv[4 * j + 1] = v.y; dtv[4 * j + 2] = v.z; dtv[4 * j + 3] = v.w;
      float4 u4 = *(const float4*)&up[ts + 4 * j];
      uv[4 * j] = u4.x; uv[4 * j + 1] = u4.y; uv[4 * j + 2] = u4.z; uv[4 * j + 3] = u4.w;
    }
#pragma unroll
    for (int i = 0; i < 16; ++i) {
      bv[i] = Bp[(size_t)(ts + i) * DS + lane];
      cv[i] = Cp[(size_t)(ts + i) * DS + lane];
    }
#pragma unroll
    for (int i = 0; i < 16; ++i) {
      float dA = EXP2(dtv[i] * An2);
      h = fmaf(dA, h, (dtv[i] * uv[i]) * bv[i]);
      sp[w][i][lane] = h * cv[i];
    }
    asm volatile("s_waitcnt lgkmcnt(0)" ::: "memory");
    __builtin_amdgcn_sched_barrier(0);
    // reduce: 4 lanes per row (timestep), 16 elems each, then quad shfl combine
    float4 a0 = *(const float4*)&sp[w][r][q * 16];
    float4 a1 = *(const float4*)&sp[w][r][q * 16 + 4];
    float4 a2 = *(const float4*)&sp[w][r][q * 16 + 8];
    float4 a3 = *(const float4*)&sp[w][r][q * 16 + 12];
    float s = ((a0.x + a0.y) + (a0.z + a0.w)) + ((a1.x + a1.y) + (a1.z + a1.w)) +
              ((a2.x + a2.y) + (a2.z + a2.w)) + ((a3.x + a3.y) + (a3.z + a3.w));
    s += __shfl_xor(s, 1);
    s += __shfl_xor(s, 2);
    if (q == 0) yp[ts + r] = s;
  }
}

// ---------------- combine: y2 = (y + u*D) * silu(z) ----------------
__global__ __launch_bounds__(256) void combine_kernel(
    const float* __restrict__ y_t, const float* __restrict__ u_t,
    const float* __restrict__ z_t, const float* __restrict__ Dv,
    float* __restrict__ y2_t) {
  int idx = blockIdx.x * 256 + threadIdx.x;
  int d = (idx >> 11) & (DI - 1);
  float y2 = fmaf(u_t[idx], Dv[d], y_t[idx]) * silu_f(z_t[idx]);
  y2_t[idx] = y2;
}

// ---------------- GEMM3: out_proj + residual ----------------
__global__ __launch_bounds__(256) void gemm_outproj(
    const float* __restrict__ y2_t, const float* __restrict__ Wo,
    const float* __restrict__ x, float* __restrict__ out) {
  __shared__ float As[16][68];  // [d][c]
  __shared__ float Bs[16][68];  // [d][l]
  int tid = threadIdx.x;
  int tx = tid & 15, ty = tid >> 4;
  int l0 = blockIdx.x * 64, c0 = blockIdx.y * 64, b = blockIdx.z;
  const float* yb = y2_t + (size_t)b * DI * LSEQ;
  float acc[4][4] = {};
  for (int k0 = 0; k0 < DI; k0 += 16) {
    {
      int kk = tid & 15, cc = tid >> 4;
#pragma unroll
      for (int i = 0; i < 4; ++i)
        As[kk][cc + 16 * i] = Wo[(size_t)(c0 + cc + 16 * i) * DI + k0 + kk];
    }
    {
      int ll = tid & 63, kk = tid >> 6;
#pragma unroll
      for (int i = 0; i < 4; ++i)
        Bs[kk + 4 * i][ll] = yb[(size_t)(k0 + kk + 4 * i) * LSEQ + l0 + ll];
    }
    __syncthreads();
#pragma unroll
    for (int k = 0; k < 16; ++k) {
      float4 a = *(const float4*)&As[k][ty * 4];   // c dir
      float4 bv = *(const float4*)&Bs[k][tx * 4];  // l dir
      float av[4] = {a.x, a.y, a.z, a.w};
      float bw[4] = {bv.x, bv.y, bv.z, bv.w};
#pragma unroll
      for (int i = 0; i < 4; ++i)
#pragma unroll
        for (int j = 0; j < 4; ++j) acc[i][j] = fmaf(av[i], bw[j], acc[i][j]);
    }
    __syncthreads();
  }
#pragma unroll
  for (int i = 0; i < 4; ++i) {
    int cc = c0 + ty * 4 + i;
    int l = l0 + tx * 4;
    size_t o = ((size_t)(b * CIN + cc)) * LSEQ + l;
    float4 xv = *(const float4*)&x[o];
    float4 v = make_float4(acc[i][0] + xv.x, acc[i][1] + xv.y,
                           acc[i][2] + xv.z, acc[i][3] + xv.w);
    *(float4*)&out[o] = v;
  }
}

extern "C" void kernel_launch(void* const* d_in, const int* in_sizes, int n_in,
                              void* d_out, int out_size, void* d_ws, size_t ws_size,
                              hipStream_t stream) {
  (void)in_sizes; (void)n_in; (void)out_size; (void)ws_size;
  const float* x = (const float*)d_in[0];
  const float* Wi = (const float*)d_in[1];
  const float* cw = (const float*)d_in[2];
  const float* cb = (const float*)d_in[3];
  const float* Wx = (const float*)d_in[4];
  const float* Wd = (const float*)d_in[5];
  const float* db = (const float*)d_in[6];
  const float* A_log = (const float*)d_in[7];
  const float* Dv = (const float*)d_in[8];
  const float* Wo = (const float*)d_in[9];
  float* out = (float*)d_out;

  float* ws = (float*)d_ws;
  size_t S = (size_t)NB * DI * LSEQ;  // 4,194,304 floats
  float* P_y = ws;               // xi_t, later y_t
  float* P_z = ws + S;
  float* P_u = ws + 2 * S;
  float* P_dt = ws + 3 * S;      // dt_t, later y2_t
  float* P_pa = ws + 4 * S;                          // NB*DI*NC*DS = 1M floats
  float* P_r = P_pa + (size_t)NB * DI * NC * DS;     // 1M floats
  float* P_dtr = P_r + (size_t)NB * DI * NC * DS;    // NB*LSEQ*8
  float* P_B = P_dtr + (size_t)NB * LSEQ * DTRANK;   // NB*LSEQ*64
  float* P_C = P_B + (size_t)NB * LSEQ * DS;

  // 1. in_proj
  gemm_inproj<<<dim3(LSEQ / 64, 1024 / 64, NB), 256, 0, stream>>>(x, Wi, P_y, P_z);
  // 2. conv + silu
  conv_silu<<<(NB * DI * LSEQ) / 256, 256, 0, stream>>>(P_y, cw, cb, P_u);
  // 3. x_proj
  gemm_xproj<<<dim3(LSEQ / 64, 3, NB), 256, 0, stream>>>(P_u, Wx, P_dtr, P_B, P_C);
  // 4. dt + softplus
  dt_kernel<<<dim3(LSEQ / 256, DI, NB), 256, 0, stream>>>(P_dtr, Wd, db, P_dt);
  // 5a. scan pass A: per-chunk (pa, r)
  scan_partial<<<dim3(DI, NC / 4, NB), 256, 0, stream>>>(P_dt, P_u, P_B, A_log, P_pa, P_r);
  // 5b. scan pass C: full scan with y (writes y into P_y, xi is dead)
  scan_full<<<dim3(DI, NC / 2, NB), 128, 0, stream>>>(P_dt, P_u, P_B, P_C, A_log, P_pa, P_r, P_y);
  // 6. combine (writes y2 into P_dt, dt is dead)
  combine_kernel<<<(NB * DI * LSEQ) / 256, 256, 0, stream>>>(P_y, P_u, P_z, Dv, P_dt);
  // 7. out_proj + residual
  gemm_outproj<<<dim3(LSEQ / 64, CIN / 64, NB), 256, 0, stream>>>(P_dt, Wo, x, out);
}